// Round 1
// baseline (160.199 us; speedup 1.0000x reference)
//
#include <hip/hip_runtime.h>
#include <math.h>

#define IMG_H 256
#define IMG_W 256
#define EPSV 1e-4f

// 48-byte per-gaussian record, written in depth-sorted order.
// q = qa*dx^2 + qb*dx*dy + qc*dy^2  (== -0.5 * mahalanobis)
// alpha = coeff * exp(q); coeff = 0 for invalid gaussians.
struct __align__(16) GData {
    float mx, my, qa, qb;
    float qc, coeff, cr, cg;
    float cb, p0, p1, p2;
};

__global__ __launch_bounds__(1024)
void GaussianRenderer_preprocess(const float* __restrict__ means3D,
                                 const float* __restrict__ covs3d,
                                 const float* __restrict__ colors,
                                 const float* __restrict__ opac,
                                 const float* __restrict__ Km,
                                 const float* __restrict__ Rm,
                                 const float* __restrict__ tv,
                                 GData* __restrict__ out, int N)
{
    __shared__ float sdepth[1024];
    const int i = threadIdx.x;

    // Uniform small matrices
    const float R00=Rm[0], R01=Rm[1], R02=Rm[2];
    const float R10=Rm[3], R11=Rm[4], R12=Rm[5];
    const float R20=Rm[6], R21=Rm[7], R22=Rm[8];
    const float K00=Km[0], K01=Km[1], K02=Km[2];
    const float K10=Km[3], K11=Km[4], K12=Km[5];
    const float K20=Km[6], K21=Km[7], K22=Km[8];
    const float fx=Km[0], fy=Km[4];
    const float t0=tv[0], t1=tv[1], t2=tv[2];

    float depth = 0.0f;
    GData gd = {};

    if (i < N) {
        const float m0 = means3D[i*3+0], m1 = means3D[i*3+1], m2 = means3D[i*3+2];
        // cam = R*m + t   (means3D @ R.T + t)
        const float c0 = R00*m0 + R01*m1 + R02*m2 + t0;
        const float c1 = R10*m0 + R11*m1 + R12*m2 + t1;
        const float c2 = R20*m0 + R21*m1 + R22*m2 + t2;
        const float z = c2;
        depth = fmaxf(z, 1.0f);

        // screen = K*cam ; means2D = screen.xy / screen.z
        const float s0 = K00*c0 + K01*c1 + K02*c2;
        const float s1 = K10*c0 + K11*c1 + K12*c2;
        const float s2 = K20*c0 + K21*c1 + K22*c2;
        const float mx = s0 / s2, my = s1 / s2;

        // Sigma_cam = R * C * R^T  (need top-left 2x2 only)
        const float* C = covs3d + i*9;
        const float C00=C[0],C01=C[1],C02=C[2],C10=C[3],C11=C[4],C12=C[5],C20=C[6],C21=C[7],C22=C[8];
        const float M00 = R00*C00 + R01*C10 + R02*C20;
        const float M01 = R00*C01 + R01*C11 + R02*C21;
        const float M02 = R00*C02 + R01*C12 + R02*C22;
        const float M10 = R10*C00 + R11*C10 + R12*C20;
        const float M11 = R10*C01 + R11*C11 + R12*C21;
        const float M12 = R10*C02 + R11*C12 + R12*C22;
        const float S00 = M00*R00 + M01*R01 + M02*R02;
        const float S01 = M00*R10 + M01*R11 + M02*R12;
        const float S10 = M10*R00 + M11*R01 + M12*R02;
        const float S11 = M10*R10 + M11*R11 + M12*R12;

        // Reference einsum is J^T Sigma J cropped to [:2,:2]; since J row 2 is zero
        // and J[0][1]=J[1][0]=0, only the diagonal fx/z, fy/z enters:
        const float j0 = fx / z, j1 = fy / z;
        const float a  = j0*j0*S00 + EPSV;
        const float b  = j0*S01*j1;
        const float cc = j1*S10*j0;
        const float d  = j1*j1*S11 + EPSV;

        const float det    = a*d - b*cc;
        const float invdet = 1.0f / det;
        const float norm   = 0.15915494309189535f / sqrtf(det);  // 1/(2*pi*sqrt(det))
        const bool valid   = (depth > 1.0f) && (depth < 50.0f);
        const float coeff  = valid ? (opac[i] * norm) : 0.0f;

        gd.mx = mx;  gd.my = my;
        gd.qa = -0.5f * d * invdet;
        gd.qb =  0.5f * (b + cc) * invdet;
        gd.qc = -0.5f * a * invdet;
        gd.coeff = coeff;
        gd.cr = colors[i*3+0];  gd.cg = colors[i*3+1];  gd.cb = colors[i*3+2];
        gd.p0 = 0.f; gd.p1 = 0.f; gd.p2 = 0.f;
    }

    sdepth[i] = depth;
    __syncthreads();

    if (i < N) {
        // stable rank == argsort position (ties broken by original index)
        int rank = 0;
        for (int j = 0; j < N; ++j) {
            const float dj = sdepth[j];
            rank += (dj < depth || (dj == depth && j < i)) ? 1 : 0;
        }
        out[rank] = gd;
    }
}

__global__ __launch_bounds__(256)
void GaussianRenderer_render(const GData* __restrict__ g,
                             float* __restrict__ out, int N)
{
    const int p = blockIdx.x * blockDim.x + threadIdx.x;
    if (p >= IMG_H * IMG_W) return;
    const float px = (float)(p % IMG_W);
    const float py = (float)(p / IMG_W);

    float T = 1.0f, ar = 0.0f, ag = 0.0f, ab = 0.0f;

    #pragma unroll 4
    for (int n = 0; n < N; ++n) {
        // wave-uniform index -> scalar loads
        const GData gd = g[n];
        const float dx = px - gd.mx;
        const float dy = py - gd.my;
        const float q  = (gd.qa*dx + gd.qb*dy)*dx + gd.qc*dy*dy;
        const float alpha = gd.coeff * __expf(q);
        const float w = alpha * T;
        ar += w * gd.cr;
        ag += w * gd.cg;
        ab += w * gd.cb;
        T  -= w;           // T *= (1 - alpha)
    }

    out[p*3 + 0] = ar;
    out[p*3 + 1] = ag;
    out[p*3 + 2] = ab;
}

extern "C" void kernel_launch(void* const* d_in, const int* in_sizes, int n_in,
                              void* d_out, int out_size, void* d_ws, size_t ws_size,
                              hipStream_t stream)
{
    const float* means3D = (const float*)d_in[0];
    const float* covs3d  = (const float*)d_in[1];
    const float* colors  = (const float*)d_in[2];
    const float* opac    = (const float*)d_in[3];
    const float* Km      = (const float*)d_in[4];
    const float* Rm      = (const float*)d_in[5];
    const float* tv      = (const float*)d_in[6];
    const int N = in_sizes[3];  // opacities: (N,)

    GData* gbuf = (GData*)d_ws;

    int threads = ((N + 63) / 64) * 64;
    if (threads > 1024) threads = 1024;  // problem fixes N=512
    GaussianRenderer_preprocess<<<1, threads, 0, stream>>>(
        means3D, covs3d, colors, opac, Km, Rm, tv, gbuf, N);

    const int total = IMG_H * IMG_W;
    GaussianRenderer_render<<<total / 256, 256, 0, stream>>>(
        gbuf, (float*)d_out, N);
}

// Round 2
// 98.735 us; speedup vs baseline: 1.6225x; 1.6225x over previous
//
#include <hip/hip_runtime.h>
#include <math.h>

#define IMG_H 256
#define IMG_W 256
#define EPSV 1e-4f
#define SEGS 8            // depth segments per pixel (1 wave each)
#define PIX_PER_BLK 64    // pixels per block (1 wave-width)

// 48-byte per-gaussian record, written in depth-sorted order.
// q = qa*dx^2 + qb*dx*dy + qc*dy^2  (== -0.5 * mahalanobis)
// alpha = coeff * exp(q); coeff = 0 for invalid gaussians.
struct __align__(16) GData {
    float mx, my, qa, qb;
    float qc, coeff, cr, cg;
    float cb, p0, p1, p2;
};

__global__ __launch_bounds__(1024)
void GaussianRenderer_preprocess(const float* __restrict__ means3D,
                                 const float* __restrict__ covs3d,
                                 const float* __restrict__ colors,
                                 const float* __restrict__ opac,
                                 const float* __restrict__ Km,
                                 const float* __restrict__ Rm,
                                 const float* __restrict__ tv,
                                 GData* __restrict__ out, int N)
{
    __shared__ float sdepth[1024];
    const int i = threadIdx.x;

    const float R00=Rm[0], R01=Rm[1], R02=Rm[2];
    const float R10=Rm[3], R11=Rm[4], R12=Rm[5];
    const float R20=Rm[6], R21=Rm[7], R22=Rm[8];
    const float K00=Km[0], K01=Km[1], K02=Km[2];
    const float K10=Km[3], K11=Km[4], K12=Km[5];
    const float K20=Km[6], K21=Km[7], K22=Km[8];
    const float fx=Km[0], fy=Km[4];
    const float t0=tv[0], t1=tv[1], t2=tv[2];

    float depth = 0.0f;
    GData gd = {};

    if (i < N) {
        const float m0 = means3D[i*3+0], m1 = means3D[i*3+1], m2 = means3D[i*3+2];
        const float c0 = R00*m0 + R01*m1 + R02*m2 + t0;
        const float c1 = R10*m0 + R11*m1 + R12*m2 + t1;
        const float c2 = R20*m0 + R21*m1 + R22*m2 + t2;
        const float z = c2;
        depth = fmaxf(z, 1.0f);

        const float s0 = K00*c0 + K01*c1 + K02*c2;
        const float s1 = K10*c0 + K11*c1 + K12*c2;
        const float s2 = K20*c0 + K21*c1 + K22*c2;
        const float mx = s0 / s2, my = s1 / s2;

        // Sigma_cam = R * C * R^T (top-left 2x2)
        const float* C = covs3d + i*9;
        const float C00=C[0],C01=C[1],C02=C[2],C10=C[3],C11=C[4],C12=C[5],C20=C[6],C21=C[7],C22=C[8];
        const float M00 = R00*C00 + R01*C10 + R02*C20;
        const float M01 = R00*C01 + R01*C11 + R02*C21;
        const float M02 = R00*C02 + R01*C12 + R02*C22;
        const float M10 = R10*C00 + R11*C10 + R12*C20;
        const float M11 = R10*C01 + R11*C11 + R12*C21;
        const float M12 = R10*C02 + R11*C12 + R12*C22;
        const float S00 = M00*R00 + M01*R01 + M02*R02;
        const float S01 = M00*R10 + M01*R11 + M02*R12;
        const float S10 = M10*R00 + M11*R01 + M12*R02;
        const float S11 = M10*R10 + M11*R11 + M12*R12;

        // Reference einsum is J^T Sigma J cropped to [:2,:2] -> only diag fx/z, fy/z enters
        const float j0 = fx / z, j1 = fy / z;
        const float a  = j0*j0*S00 + EPSV;
        const float b  = j0*S01*j1;
        const float cc = j1*S10*j0;
        const float d  = j1*j1*S11 + EPSV;

        const float det    = a*d - b*cc;
        const float invdet = 1.0f / det;
        const float norm   = 0.15915494309189535f / sqrtf(det);  // 1/(2*pi*sqrt(det))
        const bool valid   = (depth > 1.0f) && (depth < 50.0f);
        const float coeff  = valid ? (opac[i] * norm) : 0.0f;

        gd.mx = mx;  gd.my = my;
        gd.qa = -0.5f * d * invdet;
        gd.qb =  0.5f * (b + cc) * invdet;
        gd.qc = -0.5f * a * invdet;
        gd.coeff = coeff;
        gd.cr = colors[i*3+0];  gd.cg = colors[i*3+1];  gd.cb = colors[i*3+2];
        gd.p0 = 0.f; gd.p1 = 0.f; gd.p2 = 0.f;
    }

    sdepth[i] = depth;
    __syncthreads();

    if (i < N) {
        // stable rank == argsort position (ties broken by original index)
        int rank = 0;
        const int n4 = N >> 2;
        const float4* sd4 = (const float4*)sdepth;
        for (int j4 = 0; j4 < n4; ++j4) {
            const float4 v = sd4[j4];
            const int j = j4 * 4;
            rank += (v.x < depth || (v.x == depth && (j + 0) < i)) ? 1 : 0;
            rank += (v.y < depth || (v.y == depth && (j + 1) < i)) ? 1 : 0;
            rank += (v.z < depth || (v.z == depth && (j + 2) < i)) ? 1 : 0;
            rank += (v.w < depth || (v.w == depth && (j + 3) < i)) ? 1 : 0;
        }
        for (int j = n4 * 4; j < N; ++j) {
            const float dj = sdepth[j];
            rank += (dj < depth || (dj == depth && j < i)) ? 1 : 0;
        }
        out[rank] = gd;
    }
}

// Block = 512 threads = 64 pixels x 8 depth-segments (one wave per segment).
// Each wave walks its 64-gaussian segment with wave-uniform (scalar) loads,
// producing partial (rgb, T). Wave 0 composes the 8 segments via LDS.
__global__ __launch_bounds__(512)
void GaussianRenderer_render(const GData* __restrict__ g,
                             float* __restrict__ out, int N)
{
    const int seg  = __builtin_amdgcn_readfirstlane(threadIdx.x >> 6); // wave id = segment
    const int lane = threadIdx.x & 63;                                 // pixel in tile
    const int p    = blockIdx.x * PIX_PER_BLK + lane;
    const float px = (float)(p & (IMG_W - 1));
    const float py = (float)(p >> 8);   // IMG_W == 256

    const int segLen = (N + SEGS - 1) / SEGS;
    const int gBeg = seg * segLen;
    const int gEnd = (gBeg + segLen < N) ? (gBeg + segLen) : N;

    float T = 1.0f, ar = 0.0f, ag = 0.0f, ab = 0.0f;

    #pragma unroll 4
    for (int n = gBeg; n < gEnd; ++n) {
        const GData gd = g[n];          // wave-uniform -> s_load
        const float dx = px - gd.mx;
        const float dy = py - gd.my;
        const float q  = (gd.qa*dx + gd.qb*dy)*dx + gd.qc*dy*dy;
        const float alpha = gd.coeff * __expf(q);
        const float w = alpha * T;
        ar += w * gd.cr;
        ag += w * gd.cg;
        ab += w * gd.cb;
        T  -= w;                         // T *= (1 - alpha)
    }

    __shared__ float4 part[SEGS][PIX_PER_BLK];
    part[seg][lane] = make_float4(ar, ag, ab, T);
    __syncthreads();

    if (seg == 0) {
        float Tp = 1.0f, r = 0.0f, gg = 0.0f, b = 0.0f;
        #pragma unroll
        for (int s = 0; s < SEGS; ++s) {
            const float4 v = part[s][lane];
            r  += Tp * v.x;
            gg += Tp * v.y;
            b  += Tp * v.z;
            Tp *= v.w;
        }
        out[p*3 + 0] = r;
        out[p*3 + 1] = gg;
        out[p*3 + 2] = b;
    }
}

extern "C" void kernel_launch(void* const* d_in, const int* in_sizes, int n_in,
                              void* d_out, int out_size, void* d_ws, size_t ws_size,
                              hipStream_t stream)
{
    const float* means3D = (const float*)d_in[0];
    const float* covs3d  = (const float*)d_in[1];
    const float* colors  = (const float*)d_in[2];
    const float* opac    = (const float*)d_in[3];
    const float* Km      = (const float*)d_in[4];
    const float* Rm      = (const float*)d_in[5];
    const float* tv      = (const float*)d_in[6];
    const int N = in_sizes[3];  // opacities: (N,)

    GData* gbuf = (GData*)d_ws;

    int threads = ((N + 63) / 64) * 64;
    if (threads > 1024) threads = 1024;  // problem fixes N=512
    GaussianRenderer_preprocess<<<1, threads, 0, stream>>>(
        means3D, covs3d, colors, opac, Km, Rm, tv, gbuf, N);

    const int total = IMG_H * IMG_W;
    GaussianRenderer_render<<<(total + PIX_PER_BLK - 1) / PIX_PER_BLK, 512, 0, stream>>>(
        gbuf, (float*)d_out, N);
}

// Round 3
// 85.369 us; speedup vs baseline: 1.8765x; 1.1566x over previous
//
#include <hip/hip_runtime.h>
#include <math.h>

#define IMG_H 256
#define IMG_W 256
#define EPSV 1e-4f
#define SEGS 8            // depth segments per pixel (1 wave each)
#define PIX_PER_BLK 64    // pixels per block (= wave width); one row-strip
#define SKIP_EPS 1e-7f    // alpha below this may be skipped (err <= N*eps)

// 48-byte per-gaussian record, depth-sorted. Three float4s:
//  h0 = {mx, my, rx2, ry2}   cull data: skip if dxmin^2>rx2 || dy^2>ry2
//  h1 = {qa, qb, qc, coeff}  q = qa*dx^2 + qb*dx*dy + qc*dy^2 (= -0.5*mahal)
//  h2 = {cr, cg, cb, pad}    alpha = coeff*exp(q)
struct __align__(16) GData {
    float4 h0, h1, h2;
};

__global__ __launch_bounds__(1024)
void GaussianRenderer_preprocess(const float* __restrict__ means3D,
                                 const float* __restrict__ covs3d,
                                 const float* __restrict__ colors,
                                 const float* __restrict__ opac,
                                 const float* __restrict__ Km,
                                 const float* __restrict__ Rm,
                                 const float* __restrict__ tv,
                                 GData* __restrict__ out, int N)
{
    __shared__ float sdepth[1024];
    const int i = threadIdx.x;

    const float R00=Rm[0], R01=Rm[1], R02=Rm[2];
    const float R10=Rm[3], R11=Rm[4], R12=Rm[5];
    const float R20=Rm[6], R21=Rm[7], R22=Rm[8];
    const float K00=Km[0], K01=Km[1], K02=Km[2];
    const float K10=Km[3], K11=Km[4], K12=Km[5];
    const float K20=Km[6], K21=Km[7], K22=Km[8];
    const float fx=Km[0], fy=Km[4];
    const float t0=tv[0], t1=tv[1], t2=tv[2];

    float depth = 0.0f;
    GData gd = {};

    if (i < N) {
        const float m0 = means3D[i*3+0], m1 = means3D[i*3+1], m2 = means3D[i*3+2];
        const float c0 = R00*m0 + R01*m1 + R02*m2 + t0;
        const float c1 = R10*m0 + R11*m1 + R12*m2 + t1;
        const float c2 = R20*m0 + R21*m1 + R22*m2 + t2;
        const float z = c2;
        depth = fmaxf(z, 1.0f);

        const float s0 = K00*c0 + K01*c1 + K02*c2;
        const float s1 = K10*c0 + K11*c1 + K12*c2;
        const float s2 = K20*c0 + K21*c1 + K22*c2;
        const float mx = s0 / s2, my = s1 / s2;

        // Sigma_cam = R * C * R^T (top-left 2x2)
        const float* C = covs3d + i*9;
        const float C00=C[0],C01=C[1],C02=C[2],C10=C[3],C11=C[4],C12=C[5],C20=C[6],C21=C[7],C22=C[8];
        const float M00 = R00*C00 + R01*C10 + R02*C20;
        const float M01 = R00*C01 + R01*C11 + R02*C21;
        const float M02 = R00*C02 + R01*C12 + R02*C22;
        const float M10 = R10*C00 + R11*C10 + R12*C20;
        const float M11 = R10*C01 + R11*C11 + R12*C21;
        const float M12 = R10*C02 + R11*C12 + R12*C22;
        const float S00 = M00*R00 + M01*R01 + M02*R02;
        const float S01 = M00*R10 + M01*R11 + M02*R12;
        const float S10 = M10*R00 + M11*R01 + M12*R02;
        const float S11 = M10*R10 + M11*R11 + M12*R12;

        // Reference einsum is J^T Sigma J cropped to [:2,:2] -> only diag fx/z, fy/z enters
        const float j0 = fx / z, j1 = fy / z;
        const float a  = j0*j0*S00 + EPSV;   // 2D cov (incl. +EPS*I)
        const float b  = j0*S01*j1;
        const float cc = j1*S10*j0;
        const float d  = j1*j1*S11 + EPSV;

        const float det    = a*d - b*cc;
        const float invdet = 1.0f / det;
        const float norm   = 0.15915494309189535f / sqrtf(det);  // 1/(2*pi*sqrt(det))
        const bool valid   = (depth > 1.0f) && (depth < 50.0f);
        const float coeff  = valid ? (opac[i] * norm) : 0.0f;

        // Conservative cull radii via Schur bound: min_dy mahal = dx^2/a,
        // min_dx mahal = dy^2/d. alpha<eps guaranteed if dx^2 > 2*a*ln(coeff/eps).
        float rx2 = -1.0f, ry2 = -1.0f;       // -1 => always skip
        if (coeff > SKIP_EPS) {
            const float L = __logf(coeff * (1.0f / SKIP_EPS));
            rx2 = 2.0f * a * L;
            ry2 = 2.0f * d * L;
        }

        gd.h0 = make_float4(mx, my, rx2, ry2);
        gd.h1 = make_float4(-0.5f * d * invdet,
                             0.5f * (b + cc) * invdet,
                            -0.5f * a * invdet,
                            coeff);
        gd.h2 = make_float4(colors[i*3+0], colors[i*3+1], colors[i*3+2], 0.f);
    }

    sdepth[i] = depth;
    __syncthreads();

    if (i < N) {
        // stable rank == argsort position (ties broken by original index)
        int rank = 0;
        const int n4 = N >> 2;
        const float4* sd4 = (const float4*)sdepth;
        for (int j4 = 0; j4 < n4; ++j4) {
            const float4 v = sd4[j4];
            const int j = j4 * 4;
            rank += (v.x < depth || (v.x == depth && (j + 0) < i)) ? 1 : 0;
            rank += (v.y < depth || (v.y == depth && (j + 1) < i)) ? 1 : 0;
            rank += (v.z < depth || (v.z == depth && (j + 2) < i)) ? 1 : 0;
            rank += (v.w < depth || (v.w == depth && (j + 3) < i)) ? 1 : 0;
        }
        for (int j = n4 * 4; j < N; ++j) {
            const float dj = sdepth[j];
            rank += (dj < depth || (dj == depth && j < i)) ? 1 : 0;
        }
        out[rank] = gd;
    }
}

__device__ __forceinline__ float rlane(float v, int n) {
    return __int_as_float(__builtin_amdgcn_readlane(__float_as_int(v), n));
}

// Block = 512 threads = 64 pixels x 8 depth-segments (one wave per segment).
// Lane <-> gaussian: each wave loads its 64-gaussian segment coalesced into
// registers, ballots the strip-vs-ellipse cull test, then walks only the hit
// bits (depth order = ascending bit index), broadcasting params via readlane.
__global__ __launch_bounds__(512)
void GaussianRenderer_render(const GData* __restrict__ g,
                             float* __restrict__ out, int N)
{
    const int seg  = __builtin_amdgcn_readfirstlane(threadIdx.x >> 6);
    const int lane = threadIdx.x & 63;
    const int p    = blockIdx.x * PIX_PER_BLK + lane;
    const float px = (float)(p & (IMG_W - 1));
    const float py = (float)(p >> 8);                       // uniform per block
    const float cx = (float)((blockIdx.x * PIX_PER_BLK) & (IMG_W - 1)) + 31.5f;

    const int segLen = (N + SEGS - 1) / SEGS;
    const int gBeg = seg * segLen;
    const int gEnd = (gBeg + segLen < N) ? (gBeg + segLen) : N;

    float T = 1.0f, ar = 0.0f, ag = 0.0f, ab = 0.0f;

    for (int base = gBeg; base < gEnd; base += 64) {
        const int idx = base + lane;
        float4 h0 = make_float4(0.f, 0.f, -1.f, -1.f), h1 = h0, h2 = h0;
        if (idx < gEnd) {
            const GData gd = g[idx];     // coalesced: 3x global_load_dwordx4
            h0 = gd.h0; h1 = gd.h1; h2 = gd.h2;
        }
        // Strip cull: this wave covers row py, columns [cx-31.5, cx+31.5].
        const float dxm = fmaxf(fabsf(h0.x - cx) - 31.5f, 0.0f);
        const float dym = py - h0.y;
        const bool hit = (dxm * dxm <= h0.z) && (dym * dym <= h0.w);

        unsigned long long m = __ballot(hit);
        while (m) {
            const int n = __builtin_ctzll(m);
            m &= m - 1;
            const float mx = rlane(h0.x, n), my = rlane(h0.y, n);
            const float qa = rlane(h1.x, n), qb = rlane(h1.y, n);
            const float qc = rlane(h1.z, n), co = rlane(h1.w, n);
            const float cr = rlane(h2.x, n), cg = rlane(h2.y, n);
            const float cb = rlane(h2.z, n);

            const float dx = px - mx;
            const float dy = py - my;
            const float q  = (qa*dx + qb*dy)*dx + qc*(dy*dy);
            const float alpha = co * __expf(q);
            const float w = alpha * T;
            ar += w * cr;
            ag += w * cg;
            ab += w * cb;
            T  -= w;                     // T *= (1 - alpha)
        }
    }

    __shared__ float4 part[SEGS][PIX_PER_BLK];
    part[seg][lane] = make_float4(ar, ag, ab, T);
    __syncthreads();

    if (seg == 0) {
        float Tp = 1.0f, r = 0.0f, gg = 0.0f, b = 0.0f;
        #pragma unroll
        for (int s = 0; s < SEGS; ++s) {
            const float4 v = part[s][lane];
            r  += Tp * v.x;
            gg += Tp * v.y;
            b  += Tp * v.z;
            Tp *= v.w;
        }
        out[p*3 + 0] = r;
        out[p*3 + 1] = gg;
        out[p*3 + 2] = b;
    }
}

extern "C" void kernel_launch(void* const* d_in, const int* in_sizes, int n_in,
                              void* d_out, int out_size, void* d_ws, size_t ws_size,
                              hipStream_t stream)
{
    const float* means3D = (const float*)d_in[0];
    const float* covs3d  = (const float*)d_in[1];
    const float* colors  = (const float*)d_in[2];
    const float* opac    = (const float*)d_in[3];
    const float* Km      = (const float*)d_in[4];
    const float* Rm      = (const float*)d_in[5];
    const float* tv      = (const float*)d_in[6];
    const int N = in_sizes[3];  // opacities: (N,)

    GData* gbuf = (GData*)d_ws;

    int threads = ((N + 63) / 64) * 64;
    if (threads > 1024) threads = 1024;  // problem fixes N=512
    GaussianRenderer_preprocess<<<1, threads, 0, stream>>>(
        means3D, covs3d, colors, opac, Km, Rm, tv, gbuf, N);

    const int total = IMG_H * IMG_W;
    GaussianRenderer_render<<<(total + PIX_PER_BLK - 1) / PIX_PER_BLK, 512, 0, stream>>>(
        gbuf, (float*)d_out, N);
}

// Round 4
// 74.140 us; speedup vs baseline: 2.1608x; 1.1515x over previous
//
#include <hip/hip_runtime.h>
#include <math.h>

#define IMG_H 256
#define IMG_W 256
#define EPSV 1e-4f
#define SEGS 8            // depth segments per pixel (1 wave each)
#define PIX_PER_BLK 64    // pixels per block (= wave width); one row-strip
#define SKIP_EPS 1e-7f    // alpha below this may be skipped (err <= N*eps)
#define GPB 64            // gaussians ranked per preprocess block
#define MAXN 2048         // LDS depth buffer capacity (problem: N=512)

// 48-byte per-gaussian record, depth-sorted. Three float4s:
//  h0 = {mx, my, rx2, ry2}   cull data: skip if dxmin^2>rx2 || dy^2>ry2
//  h1 = {qa, qb, qc, coeff}  q = qa*dx^2 + qb*dx*dy + qc*dy^2 (= -0.5*mahal)
//  h2 = {cr, cg, cb, pad}    alpha = coeff*exp(q)
struct __align__(16) GData {
    float4 h0, h1, h2;
};

// Grid = ceil(N/64) blocks x 512 threads. Each block:
//  phase 1: all threads compute all N depths into LDS (redundant across
//           blocks -- trivial VALU, removes cross-block dependency)
//  phase 2: 8 threads per gaussian compute partial ranks (global O(N^2)
//           spread over 8 CUs instead of 1 -> LDS-BW floor /8)
//  phase 3: 64 threads compute full GData for this block's gaussians and
//           scatter-write to the depth-sorted position.
__global__ __launch_bounds__(512)
void GaussianRenderer_preprocess(const float* __restrict__ means3D,
                                 const float* __restrict__ covs3d,
                                 const float* __restrict__ colors,
                                 const float* __restrict__ opac,
                                 const float* __restrict__ Km,
                                 const float* __restrict__ Rm,
                                 const float* __restrict__ tv,
                                 GData* __restrict__ out, int N)
{
    __shared__ __align__(16) float sdepth[MAXN + 4];
    __shared__ int srank[512];

    const float R00=Rm[0], R01=Rm[1], R02=Rm[2];
    const float R10=Rm[3], R11=Rm[4], R12=Rm[5];
    const float R20=Rm[6], R21=Rm[7], R22=Rm[8];
    const float t2=tv[2];

    const int Npad = (N + 3) & ~3;

    // ---- phase 1: depths for ALL gaussians into LDS ----
    for (int i = threadIdx.x; i < Npad; i += 512) {
        float depth = __builtin_inff();           // pad: +inf never counts
        if (i < N) {
            const float m0 = means3D[i*3+0], m1 = means3D[i*3+1], m2 = means3D[i*3+2];
            const float z = R20*m0 + R21*m1 + R22*m2 + t2;
            depth = fmaxf(z, 1.0f);
        }
        sdepth[i] = depth;
    }
    __syncthreads();

    // ---- phase 2: partial ranks, 8 threads per gaussian ----
    {
        const int g   = blockIdx.x * GPB + (threadIdx.x >> 3);
        const int sub = threadIdx.x & 7;
        int rank = 0;
        if (g < N) {
            const float depth = sdepth[g];
            const int total4  = Npad >> 2;
            const int chunk4  = (total4 + 7) >> 3;
            const int b4 = sub * chunk4;
            const int e4 = (b4 + chunk4 < total4) ? (b4 + chunk4) : total4;
            const float4* sd4 = (const float4*)sdepth;
            for (int j4 = b4; j4 < e4; ++j4) {
                const float4 v = sd4[j4];
                const int j = j4 * 4;
                rank += (v.x < depth || (v.x == depth && (j + 0) < g)) ? 1 : 0;
                rank += (v.y < depth || (v.y == depth && (j + 1) < g)) ? 1 : 0;
                rank += (v.z < depth || (v.z == depth && (j + 2) < g)) ? 1 : 0;
                rank += (v.w < depth || (v.w == depth && (j + 3) < g)) ? 1 : 0;
            }
        }
        srank[threadIdx.x] = rank;
    }
    __syncthreads();

    // ---- phase 3: GData + scatter write (64 threads) ----
    const int t = threadIdx.x;
    const int i = blockIdx.x * GPB + t;
    if (t < GPB && i < N) {
        int rank = 0;
        #pragma unroll
        for (int s = 0; s < 8; ++s) rank += srank[t*8 + s];

        const float K00=Km[0], K01=Km[1], K02=Km[2];
        const float K10=Km[3], K11=Km[4], K12=Km[5];
        const float K20=Km[6], K21=Km[7], K22=Km[8];
        const float fx=Km[0], fy=Km[4];
        const float t0=tv[0], t1=tv[1];

        const float m0 = means3D[i*3+0], m1 = means3D[i*3+1], m2 = means3D[i*3+2];
        const float c0 = R00*m0 + R01*m1 + R02*m2 + t0;
        const float c1 = R10*m0 + R11*m1 + R12*m2 + t1;
        const float c2 = R20*m0 + R21*m1 + R22*m2 + t2;
        const float z = c2;
        const float depth = fmaxf(z, 1.0f);

        const float s0 = K00*c0 + K01*c1 + K02*c2;
        const float s1 = K10*c0 + K11*c1 + K12*c2;
        const float s2 = K20*c0 + K21*c1 + K22*c2;
        const float mx = s0 / s2, my = s1 / s2;

        // Sigma_cam = R * C * R^T (top-left 2x2)
        const float* C = covs3d + i*9;
        const float C00=C[0],C01=C[1],C02=C[2],C10=C[3],C11=C[4],C12=C[5],C20=C[6],C21=C[7],C22=C[8];
        const float M00 = R00*C00 + R01*C10 + R02*C20;
        const float M01 = R00*C01 + R01*C11 + R02*C21;
        const float M02 = R00*C02 + R01*C12 + R02*C22;
        const float M10 = R10*C00 + R11*C10 + R12*C20;
        const float M11 = R10*C01 + R11*C11 + R12*C21;
        const float M12 = R10*C02 + R11*C12 + R12*C22;
        const float S00 = M00*R00 + M01*R01 + M02*R02;
        const float S01 = M00*R10 + M01*R11 + M02*R12;
        const float S10 = M10*R00 + M11*R01 + M12*R02;
        const float S11 = M10*R10 + M11*R11 + M12*R12;

        // Reference einsum is J^T Sigma J cropped to [:2,:2] -> only diag fx/z, fy/z enters
        const float j0 = fx / z, j1 = fy / z;
        const float a  = j0*j0*S00 + EPSV;
        const float b  = j0*S01*j1;
        const float cc = j1*S10*j0;
        const float d  = j1*j1*S11 + EPSV;

        const float det    = a*d - b*cc;
        const float invdet = 1.0f / det;
        const float norm   = 0.15915494309189535f / sqrtf(det);  // 1/(2*pi*sqrt(det))
        const bool valid   = (depth > 1.0f) && (depth < 50.0f);
        const float coeff  = valid ? (opac[i] * norm) : 0.0f;

        // Conservative cull radii via Schur bound: alpha < SKIP_EPS guaranteed
        // outside dx^2 > 2*a*ln(coeff/eps) (resp. dy^2, d).
        float rx2 = -1.0f, ry2 = -1.0f;       // -1 => always cull
        if (coeff > SKIP_EPS) {
            const float L = __logf(coeff * (1.0f / SKIP_EPS));
            rx2 = 2.0f * a * L;
            ry2 = 2.0f * d * L;
        }

        GData gd;
        gd.h0 = make_float4(mx, my, rx2, ry2);
        gd.h1 = make_float4(-0.5f * d * invdet,
                             0.5f * (b + cc) * invdet,
                            -0.5f * a * invdet,
                            coeff);
        gd.h2 = make_float4(colors[i*3+0], colors[i*3+1], colors[i*3+2], 0.f);
        out[rank] = gd;
    }
}

__device__ __forceinline__ float rlane(float v, int n) {
    return __int_as_float(__builtin_amdgcn_readlane(__float_as_int(v), n));
}

// Block = 512 threads = 64 pixels x 8 depth-segments (one wave per segment).
// Lane <-> gaussian: each wave loads its 64-gaussian segment coalesced into
// registers, ballots the strip-vs-ellipse cull test, then walks only the hit
// bits (depth order = ascending bit index), broadcasting params via readlane.
__global__ __launch_bounds__(512)
void GaussianRenderer_render(const GData* __restrict__ g,
                             float* __restrict__ out, int N)
{
    const int seg  = __builtin_amdgcn_readfirstlane(threadIdx.x >> 6);
    const int lane = threadIdx.x & 63;
    const int p    = blockIdx.x * PIX_PER_BLK + lane;
    const float px = (float)(p & (IMG_W - 1));
    const float py = (float)(p >> 8);                       // uniform per block
    const float cx = (float)((blockIdx.x * PIX_PER_BLK) & (IMG_W - 1)) + 31.5f;

    const int segLen = (N + SEGS - 1) / SEGS;
    const int gBeg = seg * segLen;
    const int gEnd = (gBeg + segLen < N) ? (gBeg + segLen) : N;

    float T = 1.0f, ar = 0.0f, ag = 0.0f, ab = 0.0f;

    for (int base = gBeg; base < gEnd; base += 64) {
        const int idx = base + lane;
        float4 h0 = make_float4(0.f, 0.f, -1.f, -1.f), h1 = h0, h2 = h0;
        if (idx < gEnd) {
            const GData gd = g[idx];     // coalesced: 3x global_load_dwordx4
            h0 = gd.h0; h1 = gd.h1; h2 = gd.h2;
        }
        // Strip cull: this wave covers row py, columns [cx-31.5, cx+31.5].
        const float dxm = fmaxf(fabsf(h0.x - cx) - 31.5f, 0.0f);
        const float dym = py - h0.y;
        const bool hit = (dxm * dxm <= h0.z) && (dym * dym <= h0.w);

        unsigned long long m = __ballot(hit);
        while (m) {
            const int n = __builtin_ctzll(m);
            m &= m - 1;
            const float mx = rlane(h0.x, n), my = rlane(h0.y, n);
            const float qa = rlane(h1.x, n), qb = rlane(h1.y, n);
            const float qc = rlane(h1.z, n), co = rlane(h1.w, n);
            const float cr = rlane(h2.x, n), cg = rlane(h2.y, n);
            const float cb = rlane(h2.z, n);

            const float dx = px - mx;
            const float dy = py - my;
            const float q  = (qa*dx + qb*dy)*dx + qc*(dy*dy);
            const float alpha = co * __expf(q);
            const float w = alpha * T;
            ar += w * cr;
            ag += w * cg;
            ab += w * cb;
            T  -= w;                     // T *= (1 - alpha)
        }
    }

    __shared__ float4 part[SEGS][PIX_PER_BLK];
    part[seg][lane] = make_float4(ar, ag, ab, T);
    __syncthreads();

    if (seg == 0) {
        float Tp = 1.0f, r = 0.0f, gg = 0.0f, b = 0.0f;
        #pragma unroll
        for (int s = 0; s < SEGS; ++s) {
            const float4 v = part[s][lane];
            r  += Tp * v.x;
            gg += Tp * v.y;
            b  += Tp * v.z;
            Tp *= v.w;
        }
        out[p*3 + 0] = r;
        out[p*3 + 1] = gg;
        out[p*3 + 2] = b;
    }
}

extern "C" void kernel_launch(void* const* d_in, const int* in_sizes, int n_in,
                              void* d_out, int out_size, void* d_ws, size_t ws_size,
                              hipStream_t stream)
{
    const float* means3D = (const float*)d_in[0];
    const float* covs3d  = (const float*)d_in[1];
    const float* colors  = (const float*)d_in[2];
    const float* opac    = (const float*)d_in[3];
    const float* Km      = (const float*)d_in[4];
    const float* Rm      = (const float*)d_in[5];
    const float* tv      = (const float*)d_in[6];
    const int N = in_sizes[3];  // opacities: (N,)

    GData* gbuf = (GData*)d_ws;

    const int preBlocks = (N + GPB - 1) / GPB;   // 8 for N=512
    GaussianRenderer_preprocess<<<preBlocks, 512, 0, stream>>>(
        means3D, covs3d, colors, opac, Km, Rm, tv, gbuf, N);

    const int total = IMG_H * IMG_W;
    GaussianRenderer_render<<<(total + PIX_PER_BLK - 1) / PIX_PER_BLK, 512, 0, stream>>>(
        gbuf, (float*)d_out, N);
}